// Round 1
// baseline (453.930 us; speedup 1.0000x reference)
//
#include <hip/hip_runtime.h>
#include <hip/hip_bf16.h>

#define ALPHA 0.2f
#define NN 8192
#define FIN 512
#define FOUT 64

typedef __attribute__((ext_vector_type(8))) __bf16 bf16x8;
typedef __attribute__((ext_vector_type(4))) float f32x4;

// ---------------------------------------------------------------------------
// Kernel 1: wh = x @ w  (fp32), fused s1 = wh@a1, s2 = wh@a2
// 128 blocks x 256 threads; block covers 64 rows, wave = one 16-col group.
// x tile staged in LDS [kk][row] (conflict-free reads); w read via
// wave-uniform scalar loads (readfirstlane forces SGPR path).
// ---------------------------------------------------------------------------
__global__ __launch_bounds__(256) void k_wh(
    const float* __restrict__ x, const float* __restrict__ w,
    const float* __restrict__ a, float* __restrict__ wh,
    float* __restrict__ s1, float* __restrict__ s2) {
  __shared__ float xs[128][64];
  __shared__ float part1[64][4];
  __shared__ float part2[64][4];
  const int t = threadIdx.x;
  const int r = t & 63;
  const int cg = __builtin_amdgcn_readfirstlane(t >> 6);  // wave-uniform
  const int row0 = blockIdx.x * 64;

  float acc[16];
#pragma unroll
  for (int u = 0; u < 16; u++) acc[u] = 0.f;

  const int srow = t >> 2;        // 0..63
  const int scol = (t & 3) * 32;  // 0,32,64,96

  for (int kc = 0; kc < 4; kc++) {
    // stage x[row0+srow][kc*128 + scol+it*4 .. +3] -> xs[k][row]
#pragma unroll
    for (int it = 0; it < 8; it++) {
      float4 v = *(const float4*)(x + (size_t)(row0 + srow) * FIN + kc * 128 + scol + it * 4);
      xs[scol + it * 4 + 0][srow] = v.x;
      xs[scol + it * 4 + 1][srow] = v.y;
      xs[scol + it * 4 + 2][srow] = v.z;
      xs[scol + it * 4 + 3][srow] = v.w;
    }
    __syncthreads();
    const float* wp = w + (size_t)kc * 128 * FOUT + cg * 16;
    for (int kk = 0; kk < 128; kk++) {
      float av = xs[kk][r];
#pragma unroll
      for (int u = 0; u < 16; u++) acc[u] = fmaf(av, wp[kk * 64 + u], acc[u]);
    }
    __syncthreads();
  }

  // write wh (fp32)
#pragma unroll
  for (int u4 = 0; u4 < 4; u4++) {
    float4 v;
    v.x = acc[u4 * 4 + 0]; v.y = acc[u4 * 4 + 1];
    v.z = acc[u4 * 4 + 2]; v.w = acc[u4 * 4 + 3];
    *(float4*)(wh + (size_t)(row0 + r) * FOUT + cg * 16 + u4 * 4) = v;
  }

  // s1/s2 partials
  float p1 = 0.f, p2 = 0.f;
#pragma unroll
  for (int u = 0; u < 16; u++) {
    p1 = fmaf(acc[u], a[cg * 16 + u], p1);
    p2 = fmaf(acc[u], a[FOUT + cg * 16 + u], p2);
  }
  part1[r][cg] = p1;
  part2[r][cg] = p2;
  __syncthreads();
  if (t < 64) {
    s1[row0 + t] = part1[t][0] + part1[t][1] + part1[t][2] + part1[t][3];
    s2[row0 + t] = part2[t][0] + part2[t][1] + part2[t][2] + part2[t][3];
  }
}

// ---------------------------------------------------------------------------
// Kernel 2: pack wh (fp32) -> bf16 in MFMA B-fragment order.
// packB[((q*4+cg)*64 + lane)] (uint4) holds 8 bf16:
//   v -> wh[q*32 + (lane>>4)*8 + v][cg*16 + (lane&15)]
// ---------------------------------------------------------------------------
__global__ __launch_bounds__(256) void k_pack(
    const float* __restrict__ wh, uint4* __restrict__ packB) {
  const int tg = blockIdx.x * 256 + threadIdx.x;  // 0..65535
  const int lane = tg & 63;
  const int cg = (tg >> 6) & 3;
  const int q = tg >> 8;
  const int jrow = q * 32 + ((lane >> 4) * 8);
  const int col = cg * 16 + (lane & 15);
  bf16x8 v;
#pragma unroll
  for (int s = 0; s < 8; s++)
    v[s] = (__bf16)wh[(size_t)(jrow + s) * FOUT + col];
  packB[tg] = __builtin_bit_cast(uint4, v);
}

// ---------------------------------------------------------------------------
// Kernel 3: fused masked-softmax attention + PV matmul + ELU.
// 512 blocks x 256 threads; block = 16 rows; 4 waves split j 4-way (2048 each).
// Exact shift per row: shift_i = LR(s1_i + s2max) >= row max -> no online
// rescaling; partial (l, acc) merge by addition in LDS.
// ---------------------------------------------------------------------------
__global__ __launch_bounds__(256) void k_attn(
    const int* __restrict__ adj, const float* __restrict__ s1,
    const float* __restrict__ s2, const uint4* __restrict__ packB,
    float* __restrict__ out) {
  __shared__ float s2s[NN];           // 32 KB
  __shared__ float accp[4][16][64];   // 16 KB
  __shared__ float lp[4][16];
  __shared__ float wred[4];

  const int t = threadIdx.x;
  const int wv = t >> 6;
  const int lane = t & 63;

  // stage s2 into LDS + block-wide max
  float m = -1e30f;
#pragma unroll
  for (int it = 0; it < 8; it++) {
    int i4 = t + it * 256;
    float4 v = *(const float4*)&s2[i4 * 4];
    *(float4*)&s2s[i4 * 4] = v;
    m = fmaxf(m, fmaxf(fmaxf(v.x, v.y), fmaxf(v.z, v.w)));
  }
#pragma unroll
  for (int off = 32; off; off >>= 1) m = fmaxf(m, __shfl_xor(m, off));
  if (lane == 0) wred[wv] = m;
  __syncthreads();
  const float s2max = fmaxf(fmaxf(wred[0], wred[1]), fmaxf(wred[2], wred[3]));

  const int m16 = lane & 15;
  const int kb = lane >> 4;
  const int row0 = blockIdx.x * 16;
  const int i = row0 + m16;
  const float s1v = s1[i];
  float sh = s1v + s2max;
  sh = fmaxf(sh, ALPHA * sh);  // = max_j LR(s1_i + s2_j) (exact upper bound)

  f32x4 acc0 = {0.f, 0.f, 0.f, 0.f};
  f32x4 acc1 = {0.f, 0.f, 0.f, 0.f};
  f32x4 acc2 = {0.f, 0.f, 0.f, 0.f};
  f32x4 acc3 = {0.f, 0.f, 0.f, 0.f};
  float lsum = 0.f;

  const int4* adjp = (const int4*)(adj + (size_t)i * NN) + (wv * 512 + kb * 2);
  const uint4* bp = packB + (size_t)(wv * 64) * 256 + lane;
  int jj = wv * 2048 + kb * 8;

  for (int q = 0; q < 64; q++) {
    const int4 A0 = adjp[0];
    const int4 A1 = adjp[1];
    adjp += 8;
    const float4 S0 = *(const float4*)&s2s[jj];
    const float4 S1 = *(const float4*)&s2s[jj + 4];
    jj += 32;
    const uint4 B0 = bp[0];
    const uint4 B1 = bp[64];
    const uint4 B2 = bp[128];
    const uint4 B3 = bp[192];
    bp += 256;

    float sv[8] = {S0.x, S0.y, S0.z, S0.w, S1.x, S1.y, S1.z, S1.w};
    int av[8] = {A0.x, A0.y, A0.z, A0.w, A1.x, A1.y, A1.z, A1.w};
    bf16x8 af;
#pragma unroll
    for (int v = 0; v < 8; v++) {
      float e = s1v + sv[v];
      float lr = fmaxf(e, ALPHA * e);
      float pv = __expf(lr - sh);
      pv = (av[v] > 0) ? pv : 0.f;
      lsum += pv;
      af[v] = (__bf16)pv;
    }
    acc0 = __builtin_amdgcn_mfma_f32_16x16x32_bf16(af, __builtin_bit_cast(bf16x8, B0), acc0, 0, 0, 0);
    acc1 = __builtin_amdgcn_mfma_f32_16x16x32_bf16(af, __builtin_bit_cast(bf16x8, B1), acc1, 0, 0, 0);
    acc2 = __builtin_amdgcn_mfma_f32_16x16x32_bf16(af, __builtin_bit_cast(bf16x8, B2), acc2, 0, 0, 0);
    acc3 = __builtin_amdgcn_mfma_f32_16x16x32_bf16(af, __builtin_bit_cast(bf16x8, B3), acc3, 0, 0, 0);
  }

  // row-sum l: lanes m, m+16, m+32, m+48 hold partials of row m
  lsum += __shfl_xor(lsum, 16);
  lsum += __shfl_xor(lsum, 32);
  if (lane < 16) lp[wv][lane] = lsum;

  // C/D layout: col = lane&15 (within cg tile), row = kb*4 + reg
#pragma unroll
  for (int rg = 0; rg < 4; rg++) {
    accp[wv][kb * 4 + rg][0 * 16 + m16] = acc0[rg];
    accp[wv][kb * 4 + rg][1 * 16 + m16] = acc1[rg];
    accp[wv][kb * 4 + rg][2 * 16 + m16] = acc2[rg];
    accp[wv][kb * 4 + rg][3 * 16 + m16] = acc3[rg];
  }
  __syncthreads();

  // merge 4 wave-partials, normalize, ELU, store
#pragma unroll
  for (int u = 0; u < 4; u++) {
    int idx = t + u * 256;
    int rr = idx >> 6;
    int cc = idx & 63;
    float s = accp[0][rr][cc] + accp[1][rr][cc] + accp[2][rr][cc] + accp[3][rr][cc];
    float l = lp[0][rr] + lp[1][rr] + lp[2][rr] + lp[3][rr];
    float h = s / l;
    out[(size_t)(row0 + rr) * FOUT + cc] = (h > 0.f) ? h : (__expf(h) - 1.f);
  }
}

// ---------------------------------------------------------------------------
extern "C" void kernel_launch(void* const* d_in, const int* in_sizes, int n_in,
                              void* d_out, int out_size, void* d_ws, size_t ws_size,
                              hipStream_t stream) {
  const float* x = (const float*)d_in[0];
  const int* adj = (const int*)d_in[1];
  const float* w = (const float*)d_in[2];
  const float* a = (const float*)d_in[3];
  float* out = (float*)d_out;

  char* ws = (char*)d_ws;
  float* wh = (float*)ws;                               // 2 MB
  float* s1 = (float*)(ws + (size_t)NN * FOUT * 4);     // 32 KB
  float* s2 = s1 + NN;                                  // 32 KB
  uint4* packB = (uint4*)(ws + (size_t)NN * FOUT * 4 + 2 * (size_t)NN * 4);  // 1 MB

  k_wh<<<dim3(128), dim3(256), 0, stream>>>(x, w, a, wh, s1, s2);
  k_pack<<<dim3(256), dim3(256), 0, stream>>>(wh, packB);
  k_attn<<<dim3(512), dim3(256), 0, stream>>>(adj, s1, s2, packB, out);
}